// Round 25
// baseline (377.630 us; speedup 1.0000x reference)
//
#include <hip/hip_runtime.h>
#include <math.h>

typedef unsigned short u16;
typedef __attribute__((ext_vector_type(8))) short short8;
typedef __attribute__((ext_vector_type(4))) float f32x4;

__device__ __forceinline__ float bf2f(u16 u) {
  return __uint_as_float(((unsigned)u) << 16);
}
__device__ __forceinline__ u16 f2bf(float f) {
  unsigned u = __float_as_uint(f);
  return (u16)((u + 0x7fffu + ((u >> 16) & 1u)) >> 16);
}

// async global->LDS, 16B per lane. LDS dest = base + lane*16 (wave-uniform base).
__device__ __forceinline__ void gload_lds16(const u16* g, u16* l) {
  __builtin_amdgcn_global_load_lds((const __attribute__((address_space(1))) unsigned int*)g,
                                   (__attribute__((address_space(3))) unsigned int*)l, 16, 0, 0);
}

// ---------------------------------------------------------------- fused prologue
// blockIdx ranges (all 256 threads, block-uniform branch):
//   [0,8192)        cvt_x: x -> bf16 hi + lo
//   [8192,8448)     W1  transpose hi/lo  (8 x 32 tiles)
//   [8448,9472)     Wq  transpose        (32 x 32)
//   [9472,9984)     Wkv transpose        (16 x 32)
//   [9984,11008)    Wo  transpose        (32 x 32)
//   [11008,11520)   rope tables (2048 x 64)
__global__ __launch_bounds__(256) void prep_kernel(const float* __restrict__ x,
                                                   u16* __restrict__ xb,
                                                   u16* __restrict__ xlo,
                                                   const float* __restrict__ W1,
                                                   u16* __restrict__ W1Th,
                                                   u16* __restrict__ W1Tl,
                                                   const float* __restrict__ Wq,
                                                   u16* __restrict__ WqT,
                                                   const float* __restrict__ Wkv,
                                                   u16* __restrict__ WkvT,
                                                   const float* __restrict__ Wo,
                                                   u16* __restrict__ WoT,
                                                   float* __restrict__ cosT,
                                                   float* __restrict__ sinT) {
  __shared__ u16 tH[64][72];
  __shared__ u16 tL[64][72];
  int bid = blockIdx.x;
  const int t = threadIdx.x;

  if (bid < 8192) {  // cvt_x
    size_t base = ((size_t)bid * 256 + t) * 8;
    short8 hi, lo;
    #pragma unroll
    for (int i = 0; i < 8; ++i) {
      float v = x[base + i];
      u16 h = f2bf(v);
      hi[i] = (short)h;
      lo[i] = (short)f2bf(v - bf2f(h));
    }
    *(short8*)&xb[base] = hi;
    *(short8*)&xlo[base] = lo;
    return;
  }
  bid -= 8192;

  if (bid >= 2816) {  // rope tables
    int gid = (bid - 2816) * 256 + t;
    int pos = gid >> 6, i = gid & 63;
    float e = (float)(2 * i) * (1.0f / 128.0f);
    float inv = powf(10000.0f, -e);
    float ang = (float)pos * inv;
    cosT[pos * 64 + i] = cosf(ang);
    sinT[pos * 64 + i] = sinf(ang);
    return;
  }

  // transpose paths
  const float* in;
  u16* oH;
  u16* oL = nullptr;
  int R, C, bx, by;
  if (bid < 256) {
    in = W1; oH = W1Th; oL = W1Tl; R = 2048; C = 512; bx = bid & 7; by = bid >> 3;
  } else if (bid < 1280) {
    bid -= 256;
    in = Wq; oH = WqT; R = 2048; C = 2048; bx = bid & 31; by = bid >> 5;
  } else if (bid < 1792) {
    bid -= 1280;
    in = Wkv; oH = WkvT; R = 2048; C = 1024; bx = bid & 15; by = bid >> 4;
  } else {
    bid -= 1792;
    in = Wo; oH = WoT; R = 2048; C = 2048; bx = bid & 31; by = bid >> 5;
  }
  int rb = by * 64, cb = bx * 64;
  #pragma unroll
  for (int i = 0; i < 16; ++i) {
    int r = i * 4 + (t >> 6), c = t & 63;
    float v = in[(size_t)(rb + r) * C + cb + c];
    u16 h = f2bf(v);
    tH[r][c] = h;
    if (oL) tL[r][c] = f2bf(v - bf2f(h));
  }
  __syncthreads();
  #pragma unroll
  for (int i = 0; i < 16; ++i) {
    int r = i * 4 + (t >> 6), c = t & 63;
    oH[(size_t)(cb + r) * R + rb + c] = tH[c][r];
    if (oL) oL[(size_t)(cb + r) * R + rb + c] = tL[c][r];
  }
}

// ---------------------------------------------------------------- 256x256 pipelined GEMM  C = A @ B^T
template <bool BF16OUT>
__global__ __launch_bounds__(512, 2) void gemm256(const u16* __restrict__ A,
                                                  const u16* __restrict__ BT,
                                                  float* __restrict__ Cf,
                                                  u16* __restrict__ Cb,
                                                  int M, int N, int K) {
  __shared__ __align__(1024) u16 smem[65536];
  const int bm = blockIdx.x * 256, bn = blockIdx.y * 256;
  const int t = threadIdx.x, lane = t & 63, w = t >> 6;
  const int ll = lane & 15, lh = lane >> 4;
  const int wr = w >> 2, wc = w & 3;
  const int NT = K >> 6;

  const int tt0 = t, tt1 = t + 512;
  const int r0 = tt0 >> 2, r1 = tt1 >> 2;
  const int c0 = (((tt0 & 3) ^ ((tt0 >> 3) & 3)) << 3);
  const int c1 = (((tt1 & 3) ^ ((tt1 >> 3) & 3)) << 3);
  const size_t aoff0 = (size_t)(bm + r0) * K + c0;
  const size_t aoff1 = (size_t)(bm + r1) * K + c1;
  const size_t boff0 = (size_t)(bn + r0) * K + c0;
  const size_t boff1 = (size_t)(bn + r1) * K + c1;

  const int swz = ((lh ^ ((ll >> 1) & 3)) << 3);
  const int arow = (wr * 128 + ll) * 32 + swz;
  const int brow = (wc * 64 + ll) * 32 + swz;

  f32x4 acc[8][4];
  #pragma unroll
  for (int mi = 0; mi < 8; ++mi)
    #pragma unroll
    for (int ni = 0; ni < 4; ++ni) acc[mi][ni] = f32x4{0.f, 0.f, 0.f, 0.f};

  short8 aq[8], bq[2];

#define G_STAGE(base, o0, o1, lds) \
  gload_lds16((base) + (o0), (lds) + w * 512); \
  gload_lds16((base) + (o1), (lds) + 4096 + w * 512)
#define RD_A(Sa, ks) \
  _Pragma("unroll") for (int mi = 0; mi < 8; ++mi) aq[mi] = *(const short8*)&(Sa)[(ks)*8192 + arow + mi * 512]
#define RD_B(Sb, ks, nh) \
  _Pragma("unroll") for (int n2 = 0; n2 < 2; ++n2) bq[n2] = *(const short8*)&(Sb)[(ks)*8192 + brow + ((nh)*2 + n2) * 512]
#define DO_MFMA(nh) \
  __builtin_amdgcn_s_setprio(1); \
  _Pragma("unroll") for (int mi = 0; mi < 8; ++mi) \
    _Pragma("unroll") for (int n2 = 0; n2 < 2; ++n2) \
      acc[mi][(nh)*2 + n2] = __builtin_amdgcn_mfma_f32_16x16x32_bf16(aq[mi], bq[n2], acc[mi][(nh)*2 + n2], 0, 0, 0); \
  __builtin_amdgcn_s_setprio(0)
#define VMW(n) asm volatile("s_waitcnt vmcnt(" #n ")" ::: "memory")

  G_STAGE(A, aoff0, aoff1, smem);
  G_STAGE(BT, boff0, boff1, smem + 16384);
  G_STAGE(A, aoff0 + 32, aoff1 + 32, smem + 8192);
  G_STAGE(BT, boff0 + 32, boff1 + 32, smem + 16384 + 8192);

  for (int kt = 0; kt < NT - 1; ++kt) {
    const int cur = kt & 1;
    u16* Sa = smem + cur * 32768;
    u16* Sb = Sa + 16384;
    u16* Pa = smem + (cur ^ 1) * 32768;
    u16* Pb = Pa + 16384;
    const size_t kg = (size_t)(kt + 1) * 64;
    VMW(4);
    __builtin_amdgcn_s_barrier();
    G_STAGE(A, aoff0 + kg, aoff1 + kg, Pa);
    RD_A(Sa, 0);
    RD_B(Sb, 0, 0);
    DO_MFMA(0);
    __builtin_amdgcn_s_barrier();
    G_STAGE(BT, boff0 + kg, boff1 + kg, Pb);
    RD_B(Sb, 0, 1);
    DO_MFMA(1);
    VMW(4);
    __builtin_amdgcn_s_barrier();
    G_STAGE(A, aoff0 + kg + 32, aoff1 + kg + 32, Pa + 8192);
    RD_A(Sa, 1);
    RD_B(Sb, 1, 0);
    DO_MFMA(0);
    __builtin_amdgcn_s_barrier();
    G_STAGE(BT, boff0 + kg + 32, boff1 + kg + 32, Pb + 8192);
    RD_B(Sb, 1, 1);
    DO_MFMA(1);
  }
  {
    const int cur = (NT - 1) & 1;
    u16* Sa = smem + cur * 32768;
    u16* Sb = Sa + 16384;
    VMW(4);
    __builtin_amdgcn_s_barrier();
    RD_A(Sa, 0); RD_B(Sb, 0, 0); DO_MFMA(0);
    __builtin_amdgcn_s_barrier();
    RD_B(Sb, 0, 1); DO_MFMA(1);
    VMW(0);
    __builtin_amdgcn_s_barrier();
    RD_A(Sa, 1); RD_B(Sb, 1, 0); DO_MFMA(0);
    __builtin_amdgcn_s_barrier();
    RD_B(Sb, 1, 1); DO_MFMA(1);
  }

  #pragma unroll
  for (int mi = 0; mi < 8; ++mi)
    #pragma unroll
    for (int ni = 0; ni < 4; ++ni)
      #pragma unroll
      for (int r = 0; r < 4; ++r) {
        int row = bm + wr * 128 + mi * 16 + lh * 4 + r;
        int col = bn + wc * 64 + ni * 16 + ll;
        float v = acc[mi][ni][r];
        if (BF16OUT) Cb[(size_t)row * N + col] = f2bf(v);
        else Cf[(size_t)row * N + col] = v;
      }
#undef G_STAGE
#undef RD_A
#undef RD_B
#undef DO_MFMA
#undef VMW
}

// ---------------------------------------------------------------- gathered-A GEMM (split-K, pipelined async)
__global__ __launch_bounds__(256) void gemm_bt_gather(const u16* __restrict__ A,
                                                      const u16* __restrict__ BT,
                                                      const int* __restrict__ rowidx,
                                                      float* __restrict__ Cpart,
                                                      int M, int N, int K) {
  __shared__ __align__(1024) u16 smem[32768];  // 2 bufs x (A 8192 + B 8192)
  const int bm = blockIdx.x * 128, bn = blockIdx.y * 128;
  const int kz = blockIdx.z;
  const int t = threadIdx.x, lane = t & 63, w = t >> 6;
  const int lh = lane >> 4, ll = lane & 15;
  const int wm = (w >> 1) * 64, wn = (w & 1) * 64;

  size_t aoff[4], boff[4];
  #pragma unroll
  for (int i = 0; i < 4; ++i) {
    int c = i * 256 + t;
    int row = c >> 3;
    int gslot = (c & 7) ^ (row & 7);
    aoff[i] = (size_t)rowidx[bm + row] * K + gslot * 8;
    boff[i] = (size_t)(bn + row) * K + gslot * 8;
  }

  f32x4 acc[4][4];
  #pragma unroll
  for (int mt = 0; mt < 4; ++mt)
    #pragma unroll
    for (int nt = 0; nt < 4; ++nt) acc[mt][nt] = f32x4{0.f, 0.f, 0.f, 0.f};

#define GA_STAGE(buf, kb) \
  _Pragma("unroll") for (int i = 0; i < 4; ++i) { \
    int c = i * 256 + t; \
    gload_lds16(A + aoff[i] + (kb), (buf) + c * 8); \
    gload_lds16(BT + boff[i] + (kb), (buf) + 8192 + c * 8); \
  }
#define GVMW(n) asm volatile("s_waitcnt vmcnt(" #n ")" ::: "memory")

  const int k0 = kz * (K / 2);
  const int NT = (K / 2) / 64;  // 16

  GA_STAGE(smem, k0);

  for (int kt = 0; kt < NT; ++kt) {
    const int cur = kt & 1;
    u16* S = smem + cur * 16384;
    if (kt + 1 < NT) {
      GA_STAGE(smem + (cur ^ 1) * 16384, k0 + (kt + 1) * 64);
      GVMW(8);
    } else {
      GVMW(0);
    }
    __builtin_amdgcn_s_barrier();
    #pragma unroll
    for (int ks = 0; ks < 2; ++ks) {
      short8 a[4], b[4];
      #pragma unroll
      for (int mt = 0; mt < 4; ++mt) {
        int row = wm + mt * 16 + ll;
        int p = (ks * 4 + lh) ^ (row & 7);
        a[mt] = *(const short8*)&S[row * 64 + p * 8];
      }
      #pragma unroll
      for (int nt = 0; nt < 4; ++nt) {
        int row = wn + nt * 16 + ll;
        int p = (ks * 4 + lh) ^ (row & 7);
        b[nt] = *(const short8*)&S[8192 + row * 64 + p * 8];
      }
      __builtin_amdgcn_s_setprio(1);
      #pragma unroll
      for (int mt = 0; mt < 4; ++mt)
        #pragma unroll
        for (int nt = 0; nt < 4; ++nt)
          acc[mt][nt] = __builtin_amdgcn_mfma_f32_16x16x32_bf16(a[mt], b[nt], acc[mt][nt], 0, 0, 0);
      __builtin_amdgcn_s_setprio(0);
    }
    __builtin_amdgcn_s_barrier();
  }

  float* C = Cpart + (size_t)kz * M * N;
  #pragma unroll
  for (int mt = 0; mt < 4; ++mt)
    #pragma unroll
    for (int nt = 0; nt < 4; ++nt)
      #pragma unroll
      for (int r = 0; r < 4; ++r) {
        int row = bm + wm + mt * 16 + lh * 4 + r;
        int col = bn + wn + nt * 16 + ll;
        C[(size_t)row * N + col] = acc[mt][nt][r];
      }
#undef GA_STAGE
#undef GVMW
}

// ---------------------------------------------------------------- scorer GEMM (3-term hi/lo, depth-2 pipeline)
__global__ __launch_bounds__(512) void gemm_scorer(const u16* __restrict__ Ahi,
                                                   const u16* __restrict__ Alo,
                                                   const u16* __restrict__ Bhi,
                                                   const u16* __restrict__ Blo,
                                                   float* __restrict__ Cpart,
                                                   int M, int N, int K) {
  __shared__ __align__(1024) u16 smem[73728];  // 3 bufs x 24576 elems
  const int bm = blockIdx.x * 256, bn = blockIdx.y * 128;
  const int kz = blockIdx.z;
  const int t = threadIdx.x, lane = t & 63, w = t >> 6;
  const int ll = lane & 15, lh = lane >> 4;
  const int wr = w >> 2, wc = w & 3;

  const int cA0 = (w * 2) * 64 + lane;
  const int cA1 = (w * 2 + 1) * 64 + lane;
  const int cB = w * 64 + lane;
  const size_t offA0 = (size_t)(bm + (cA0 >> 2)) * K + (((cA0 & 3) ^ ((cA0 >> 3) & 3)) << 3);
  const size_t offA1 = (size_t)(bm + (cA1 >> 2)) * K + (((cA1 & 3) ^ ((cA1 >> 3) & 3)) << 3);
  const size_t offB = (size_t)(bn + (cB >> 2)) * K + (((cB & 3) ^ ((cB >> 3) & 3)) << 3);

  const int arow = wr * 128 + ll;
  const int brow = wc * 32 + ll;

  f32x4 acc[8][2];
  #pragma unroll
  for (int mi = 0; mi < 8; ++mi)
    #pragma unroll
    for (int ni = 0; ni < 2; ++ni) acc[mi][ni] = f32x4{0.f, 0.f, 0.f, 0.f};

#define S_STAGE(buf, kb) \
  gload_lds16(Ahi + offA0 + (kb), (buf) + cA0 * 8); \
  gload_lds16(Ahi + offA1 + (kb), (buf) + cA1 * 8); \
  gload_lds16(Alo + offA0 + (kb), (buf) + 8192 + cA0 * 8); \
  gload_lds16(Alo + offA1 + (kb), (buf) + 8192 + cA1 * 8); \
  gload_lds16(Bhi + offB + (kb), (buf) + 16384 + cB * 8); \
  gload_lds16(Blo + offB + (kb), (buf) + 20480 + cB * 8)
#define SVMW(n) asm volatile("s_waitcnt vmcnt(" #n ")" ::: "memory")

  const int k0 = kz * (K / 2);
  const int NT = (K / 2) / 32;  // 32

  S_STAGE(smem, k0);
  S_STAGE(smem + 24576, k0 + 32);

  for (int kt = 0; kt < NT; ++kt) {
    u16* S = smem + (kt % 3) * 24576;
    if (kt + 1 < NT) { SVMW(6); } else { SVMW(0); }
    __builtin_amdgcn_s_barrier();
    if (kt + 2 < NT) { S_STAGE(smem + ((kt + 2) % 3) * 24576, k0 + (kt + 2) * 32); }

    short8 aH[8], aL[8], bH[2], bL[2];
    #pragma unroll
    for (int mi = 0; mi < 8; ++mi) {
      int r = arow + mi * 16;
      int o = r * 32 + ((lh ^ ((r >> 1) & 3)) << 3);
      aH[mi] = *(const short8*)&S[o];
      aL[mi] = *(const short8*)&S[8192 + o];
    }
    #pragma unroll
    for (int ni = 0; ni < 2; ++ni) {
      int r = brow + ni * 16;
      int o = r * 32 + ((lh ^ ((r >> 1) & 3)) << 3);
      bH[ni] = *(const short8*)&S[16384 + o];
      bL[ni] = *(const short8*)&S[20480 + o];
    }
    __builtin_amdgcn_s_setprio(1);
    #pragma unroll
    for (int mi = 0; mi < 8; ++mi)
      #pragma unroll
      for (int ni = 0; ni < 2; ++ni)
        acc[mi][ni] = __builtin_amdgcn_mfma_f32_16x16x32_bf16(aH[mi], bH[ni], acc[mi][ni], 0, 0, 0);
    __builtin_amdgcn_s_setprio(0);
    __builtin_amdgcn_s_setprio(1);
    #pragma unroll
    for (int mi = 0; mi < 8; ++mi)
      #pragma unroll
      for (int ni = 0; ni < 2; ++ni)
        acc[mi][ni] = __builtin_amdgcn_mfma_f32_16x16x32_bf16(aH[mi], bL[ni], acc[mi][ni], 0, 0, 0);
    __builtin_amdgcn_s_setprio(0);
    __builtin_amdgcn_s_setprio(1);
    #pragma unroll
    for (int mi = 0; mi < 8; ++mi)
      #pragma unroll
      for (int ni = 0; ni < 2; ++ni)
        acc[mi][ni] = __builtin_amdgcn_mfma_f32_16x16x32_bf16(aL[mi], bH[ni], acc[mi][ni], 0, 0, 0);
    __builtin_amdgcn_s_setprio(0);
    __builtin_amdgcn_s_barrier();
  }

  float* C = Cpart + (size_t)kz * M * N;
  #pragma unroll
  for (int mi = 0; mi < 8; ++mi)
    #pragma unroll
    for (int ni = 0; ni < 2; ++ni)
      #pragma unroll
      for (int r = 0; r < 4; ++r) {
        int row = bm + wr * 128 + mi * 16 + lh * 4 + r;
        int col = bn + wc * 32 + ni * 16 + ll;
        C[(size_t)row * N + col] = acc[mi][ni][r];
      }
#undef S_STAGE
#undef SVMW
}

// ---------------------------------------------------------------- scorer finish
__global__ __launch_bounds__(256) void scorer_finish(const float* __restrict__ hg,
                                                     const float* __restrict__ b1,
                                                     const float* __restrict__ W2,
                                                     const float* __restrict__ b2,
                                                     float* __restrict__ imp) {
  int tok = blockIdx.x * 4 + (threadIdx.x >> 6);
  int lane = threadIdx.x & 63;
  const float* h0 = hg + (size_t)tok * 512;
  const float* h1 = hg + (size_t)8192 * 512 + (size_t)tok * 512;
  float s = 0.f;
  #pragma unroll
  for (int i = 0; i < 8; ++i) {
    int c = lane + i * 64;
    float v = h0[c] + h1[c] + b1[c];
    v = 0.5f * v * (1.0f + erff(v * 0.70710678118654752f));
    s += v * W2[c];
  }
  #pragma unroll
  for (int off = 32; off; off >>= 1) s += __shfl_xor(s, off, 64);
  if (lane == 0) imp[tok] = s + b2[0];
}

// ---------------------------------------------------------------- top-k (exact, bitonic)
__global__ __launch_bounds__(1024) void topk_kernel(const float* __restrict__ imp,
                                                    int* __restrict__ idx_sel,
                                                    int* __restrict__ sel_rows,
                                                    float* __restrict__ gatev) {
  __shared__ float v[2048];
  __shared__ int ix[2048];
  __shared__ int ids[512];
  int b = blockIdx.x, t = threadIdx.x;
  for (int i = t; i < 2048; i += 1024) { v[i] = imp[b * 2048 + i]; ix[i] = i; }
  __syncthreads();
  for (int k = 2; k <= 2048; k <<= 1)
    for (int j = k >> 1; j > 0; j >>= 1) {
      int i = ((t & ~(j - 1)) << 1) | (t & (j - 1));
      int l2 = i | j;
      bool dir = ((i & k) == 0);
      float vi = v[i], vl = v[l2];
      int xi = ix[i], xl = ix[l2];
      bool g = (vi < vl) || (vi == vl && xi > xl);
      if (g == dir) { v[i] = vl; v[l2] = vi; ix[i] = xl; ix[l2] = xi; }
      __syncthreads();
    }
  if (t < 512) ids[t] = ix[t];
  __syncthreads();
  for (int k = 2; k <= 512; k <<= 1)
    for (int j = k >> 1; j > 0; j >>= 1) {
      if (t < 256) {
        int i = ((t & ~(j - 1)) << 1) | (t & (j - 1));
        int l2 = i | j;
        bool dir = ((i & k) == 0);
        int ai = ids[i], al = ids[l2];
        if ((ai > al) == dir) { ids[i] = al; ids[l2] = ai; }
      }
      __syncthreads();
    }
  if (t < 512) {
    int id = ids[t];
    idx_sel[b * 512 + t] = id;
    sel_rows[b * 512 + t] = b * 2048 + id;
    float g = imp[b * 2048 + id];
    gatev[b * 512 + t] = 1.0f / (1.0f + __expf(-g));
  }
}

// ---------------------------------------------------------------- fused K-rope + gated V^T from fp32 partials
__global__ __launch_bounds__(256) void kv_finish(const float* __restrict__ part,
                                                 const int* __restrict__ idx_sel,
                                                 const float* __restrict__ cosT,
                                                 const float* __restrict__ sinT,
                                                 const float* __restrict__ gatev,
                                                 u16* __restrict__ Kb,
                                                 u16* __restrict__ VT) {
  int gid = blockIdx.x * 256 + threadIdx.x;
  if (gid < (1 << 19)) {
    int i = gid & 63;
    int s = (gid >> 6) & 511;
    int kvh = (gid >> 15) & 3;
    int b = gid >> 17;
    size_t src = (size_t)(b * 512 + s) * 1024 + kvh * 128 + i;
    float k1 = part[src] + part[src + 2097152];
    float k2 = part[src + 64] + part[src + 64 + 2097152];
    int pos = idx_sel[b * 512 + s];
    float c = cosT[pos * 64 + i], sn = sinT[pos * 64 + i];
    size_t dst = (size_t)((b * 4 + kvh) * 512 + s) * 128 + i;
    Kb[dst] = f2bf(k1 * c - k2 * sn);
    Kb[dst + 64] = f2bf(k1 * sn + k2 * c);
  } else {
    int g2 = gid - (1 << 19);
    int s = g2 & 511;
    int d = (g2 >> 9) & 127;
    int kvh = (g2 >> 16) & 3;
    int b = g2 >> 18;
    size_t src = (size_t)(b * 512 + s) * 1024 + 512 + kvh * 128 + d;
    float v = part[src] + part[src + 2097152];
    VT[(size_t)((b * 4 + kvh) * 128 + d) * 512 + s] = f2bf(v * gatev[b * 512 + s]);
  }
}

// ---------------------------------------------------------------- flash attention
// grid (16 qtiles of 128, 16 heads, 4 batch), 512 threads = 8 waves x 16 q rows.
// r13 pads (best measured): Ks[132], Vs[76], Ps[68]. LDS 54,016B -> 3 blocks/CU.
// qt de-aliased. idx_s staged. Fused RoPE-Q. Defer-rescale THR=8. T5 setprio.
__global__ __launch_bounds__(512) void attn_kernel(const u16* __restrict__ Qb,
                                                   const u16* __restrict__ Kb,
                                                   const u16* __restrict__ VTb,
                                                   const int* __restrict__ idxp,
                                                   const float* __restrict__ cosT,
                                                   const float* __restrict__ sinT,
                                                   u16* __restrict__ Ob) {
  __shared__ u16 Ks[64][132];   // 16896B
  __shared__ u16 Vs[128][76];   // 19456B
  __shared__ u16 Ps[8][16][68]; // 17408B
  __shared__ int idx_s[64];     // 256B   -> total 54016B, 3 blocks/CU

  const int qt = (blockIdx.x + 4 * blockIdx.z) & 15;  // de-alias qt from CU id
  const int h = blockIdx.y, b = blockIdx.z;
  const int kvh = h >> 2;
  const int t = threadIdx.x, lane = t & 63, w = t >> 6;
  const int lh = lane >> 4, ll = lane & 15;
  const int q0 = qt * 128;
  const float SCALE_LOG2E = 0.12753102331f;  // HD^-0.5 * log2(e)

  int NT = 8;
  if (idxp[b * 512] <= q0) {
    NT = 1;
    while (NT < 8 && idxp[b * 512 + NT * 64] <= q0 + 127) ++NT;
  }

  const int lrow = q0 + w * 16 + ll;
  short8 aq[4];
  #pragma unroll
  for (int ks = 0; ks < 4; ++ks)
    aq[ks] = *(const short8*)&Qb[(size_t)(b * 2048 + lrow) * 2048 + h * 128 + ks * 32 + lh * 8];
  {
    const float* cp = cosT + (size_t)lrow * 64 + lh * 8;
    const float* sp = sinT + (size_t)lrow * 64 + lh * 8;
    short8 n0, n1, n2, n3;
    #pragma unroll
    for (int j = 0; j < 8; ++j) {
      float cA = cp[j], sA = sp[j], cB = cp[32 + j], sB = sp[32 + j];
      float x0 = bf2f((u16)aq[0][j]), x2 = bf2f((u16)aq[2][j]);
      float x1 = bf2f((u16)aq[1][j]), x3 = bf2f((u16)aq[3][j]);
      n0[j] = (short)f2bf(x0 * cA - x2 * sA);
      n2[j] = (short)f2bf(x0 * sA + x2 * cA);
      n1[j] = (short)f2bf(x1 * cB - x3 * sB);
      n3[j] = (short)f2bf(x1 * sB + x3 * cB);
    }
    aq[0] = n0; aq[1] = n1; aq[2] = n2; aq[3] = n3;
  }

  float m[4], lden[4];
  f32x4 O[8];
  #pragma unroll
  for (int r = 0; r < 4; ++r) { m[r] = -INFINITY; lden[r] = 0.f; }
  #pragma unroll
  for (int dt = 0; dt < 8; ++dt) O[dt] = f32x4{0.f, 0.f, 0.f, 0.f};

  for (int kt = 0; kt < NT; ++kt) {
    const int tmax = idxp[b * 512 + kt * 64 + 63];
    const bool nomask = (tmax <= q0 + w * 16);  // wave-uniform

    __syncthreads();
    #pragma unroll
    for (int i = 0; i < 2; ++i) {
      int e = t + i * 512;
      int krow = e >> 4, kc8 = e & 15;
      *(short8*)&Ks[krow][kc8 * 8] =
          *(const short8*)&Kb[(size_t)((b * 4 + kvh) * 512 + kt * 64 + krow) * 128 + kc8 * 8];
      int vrow = e >> 3, vc8 = e & 7;
      *(short8*)&Vs[vrow][vc8 * 8] =
          *(const short8*)&VTb[(size_t)((b * 4 + kvh) * 128 + vrow) * 512 + kt * 64 + vc8 * 8];
    }
    if (t < 64) idx_s[t] = idxp[b * 512 + kt * 64 + t];
    __syncthreads();

    f32x4 S[4];
    #pragma unroll
    for (int nt = 0; nt < 4; ++nt) S[nt] = f32x4{0.f, 0.f, 0.f, 0.f};
    __builtin_amdgcn_s_setprio(1);
    #pragma unroll
    for (int nt = 0; nt < 4; ++nt)
      #pragma unroll
      for (int ks = 0; ks < 4; ++ks) {
        short8 bk = *(const short8*)&Ks[nt * 16 + ll][ks * 32 + lh * 8];
        S[nt] = __builtin_amdgcn_mfma_f32_16x16x32_bf16(aq[ks], bk, S[nt], 0, 0, 0);
      }
    __builtin_amdgcn_s_setprio(0);

    float p[4][4], lmax[4];
    #pragma unroll
    for (int r = 0; r < 4; ++r) lmax[r] = -INFINITY;
    if (nomask) {
      #pragma unroll
      for (int nt = 0; nt < 4; ++nt)
        #pragma unroll
        for (int r = 0; r < 4; ++r) {
          float s = S[nt][r] * SCALE_LOG2E;
          p[nt][r] = s;
          lmax[r] = fmaxf(lmax[r], s);
        }
    } else {
      #pragma unroll
      for (int nt = 0; nt < 4; ++nt) {
        int kpos = idx_s[nt * 16 + ll];
        #pragma unroll
        for (int r = 0; r < 4; ++r) {
          int row = q0 + w * 16 + lh * 4 + r;
          float s = S[nt][r] * SCALE_LOG2E;
          if (kpos > row) s = -1e9f;
          p[nt][r] = s;
          lmax[r] = fmaxf(lmax[r], s);
        }
      }
    }
    #pragma unroll
    for (int off = 8; off; off >>= 1)
      #pragma unroll
      for (int r = 0; r < 4; ++r) lmax[r] = fmaxf(lmax[r], __shfl_xor(lmax[r], off, 64));

    bool need = false;
    #pragma unroll
    for (int r = 0; r < 4; ++r) need = need || (lmax[r] > m[r] + 8.0f);
    if (__any(need)) {
      #pragma unroll
      for (int r = 0; r < 4; ++r) {
        float mnew = fmaxf(m[r], lmax[r]);
        float alpha = exp2f(m[r] - mnew);
        m[r] = mnew;
        lden[r] *= alpha;
        #pragma unroll
        for (int dt = 0; dt < 8; ++dt) O[dt][r] *= alpha;
      }
    }

    float rs[4] = {0.f, 0.f, 0.f, 0.f};
    #pragma unroll
    for (int nt = 0; nt < 4; ++nt)
      #pragma unroll
      for (int r = 0; r < 4; ++r) {
        float e = exp2f(p[nt][r] - m[r]);
        p[nt][r] = e;
        rs[r] += e;
      }
    #pragma unroll
    for (int off = 8; off; off >>= 1)
      #pragma unroll
      for (int r = 0; r < 4; ++r) rs[r] += __shfl_xor(rs[r], off, 64);
    #pragma unroll
    for (int r = 0; r < 4; ++r) lden[r] += rs[r];

    #pragma unroll
    for (int nt = 0; nt < 4; ++nt)
      #pragma unroll
      for (int r = 0; r < 4; r += 2) {
        unsigned pk;
        asm("v_cvt_pk_bf16_f32 %0, %1, %2" : "=v"(pk) : "v"(p[nt][r]), "v"(p[nt][r + 1]));
        Ps[w][lh * 4 + r][nt * 16 + ll] = (u16)pk;
        Ps[w][lh * 4 + r + 1][nt * 16 + ll] = (u16)(pk >> 16);
      }
    __builtin_amdgcn_s_setprio(1);
    #pragma unroll
    for (int ks = 0; ks < 2; ++ks) {
      short8 pa = *(const short8*)&Ps[w][ll][ks * 32 + lh * 8];
      #pragma unroll
      for (int dt = 0; dt < 8; ++dt) {
        short8 vb = *(const short8*)&Vs[dt * 16 + ll][ks * 32 + lh * 8];
        O[dt] = __builtin_amdgcn_mfma_f32_16x16x32_bf16(pa, vb, O[dt], 0, 0, 0);
      }
    }
    __builtin_amdgcn_s_setprio(0);
  }

  #pragma unroll
  for (int dt = 0; dt < 8; ++dt)
    #pragma unroll
    for (int r = 0; r < 4; ++r) {
      int row = q0 + w * 16 + lh * 4 + r;
      int col = h * 128 + dt * 16 + ll;
      Ob[(size_t)(b * 2048 + row) * 2048 + col] = f2bf(O[dt][r] / lden[r]);
    }
}

// ================================================================ launch
extern "C" void kernel_launch(void* const* d_in, const int* in_sizes, int n_in,
                              void* d_out, int out_size, void* d_ws, size_t ws_size,
                              hipStream_t stream) {
  const float* x = (const float*)d_in[0];
  const float* Wq = (const float*)d_in[1];
  const float* Wkv = (const float*)d_in[2];
  const float* Wo = (const float*)d_in[3];
  const float* W1 = (const float*)d_in[4];
  const float* b1 = (const float*)d_in[5];
  const float* W2 = (const float*)d_in[6];
  const float* b2 = (const float*)d_in[7];
  float* out = (float*)d_out;

  char* ws = (char*)d_ws;
  size_t off = 0;
  auto alloc = [&](size_t bytes) {
    char* p = ws + off;
    off = (off + bytes + 255) & ~(size_t)255;
    return p;
  };
  u16* xb = (u16*)alloc((size_t)8192 * 2048 * 2);
  u16* xlo = (u16*)alloc((size_t)8192 * 2048 * 2);   // dead after scorer GEMM
  u16* W1Th = (u16*)alloc((size_t)512 * 2048 * 2);
  u16* W1Tl = (u16*)alloc((size_t)512 * 2048 * 2);
  u16* WqT = (u16*)alloc((size_t)2048 * 2048 * 2);
  u16* WkvT = (u16*)alloc((size_t)1024 * 2048 * 2);
  u16* WoT = (u16*)alloc((size_t)2048 * 2048 * 2);
  float* cosT = (float*)alloc((size_t)2048 * 64 * 4);
  float* sinT = (float*)alloc((size_t)2048 * 64 * 4);
  float* hg = (float*)alloc((size_t)2 * 8192 * 512 * 4);  // scorer partials; later reused for kv partials
  float* impv = (float*)alloc((size_t)8192 * 4);
  int* idx_sel = (int*)alloc((size_t)2048 * 4);
  int* sel_rows = (int*)alloc((size_t)2048 * 4);
  float* gatev = (float*)alloc((size_t)2048 * 4);
  u16* qbuf = (u16*)alloc((size_t)8192 * 2048 * 2);
  u16* Kbuf = (u16*)alloc((size_t)4 * 4 * 512 * 128 * 2);
  u16* VTbuf = (u16*)alloc((size_t)4 * 4 * 128 * 512 * 2);
  u16* attn_out = xlo;          // alias: xlo dead before attention writes
  float* kvpart = hg;           // alias: hg dead after topk (needs 16MB of hg's 32MB)

  // fused prologue: cvt_x + 4 weight transposes + rope tables in ONE launch
  prep_kernel<<<11520, 256, 0, stream>>>(x, xb, xlo, W1, W1Th, W1Tl, Wq, WqT,
                                         Wkv, WkvT, Wo, WoT, cosT, sinT);

  // scorer: depth-2 pipelined split-K partials, then fused finish (bias+gelu+W2+b2)
  gemm_scorer<<<dim3(32, 4, 2), 512, 0, stream>>>(xb, xlo, W1Th, W1Tl, hg, 8192, 512, 2048);
  scorer_finish<<<2048, 256, 0, stream>>>(hg, b1, W2, b2, impv);
  topk_kernel<<<4, 1024, 0, stream>>>(impv, idx_sel, sel_rows, gatev);

  // q = x@Wq (bf16, 256x256 pipelined); RoPE applied inside attention
  gemm256<true><<<dim3(32, 8), 512, 0, stream>>>(xb, WqT, nullptr, qbuf, 8192, 2048, 2048);

  // kv on gathered rows (pipelined split-K fp32 partials), then fused K-rope + gated V^T
  gemm_bt_gather<<<dim3(16, 8, 2), 256, 0, stream>>>(xb, WkvT, sel_rows, kvpart, 2048, 1024, 2048);
  kv_finish<<<6144, 256, 0, stream>>>(kvpart, idx_sel, cosT, sinT, gatev, Kbuf, VTbuf);

  // attention (LDS-staged, 3 blocks/CU, qt de-aliased, fused RoPE-Q, T5 setprio)
  attn_kernel<<<dim3(16, 16, 4), 512, 0, stream>>>(qbuf, Kbuf, VTbuf, idx_sel, cosT, sinT, attn_out);

  // output projection -> fp32 d_out (256x256 pipelined, phase-split)
  gemm256<false><<<dim3(32, 8), 512, 0, stream>>>(attn_out, WoT, out, nullptr, 8192, 2048, 2048);
}

// Round 26
// 356.757 us; speedup vs baseline: 1.0585x; 1.0585x over previous
//
#include <hip/hip_runtime.h>
#include <math.h>

typedef unsigned short u16;
typedef __attribute__((ext_vector_type(8))) short short8;
typedef __attribute__((ext_vector_type(4))) float f32x4;

__device__ __forceinline__ float bf2f(u16 u) {
  return __uint_as_float(((unsigned)u) << 16);
}
__device__ __forceinline__ u16 f2bf(float f) {
  unsigned u = __float_as_uint(f);
  return (u16)((u + 0x7fffu + ((u >> 16) & 1u)) >> 16);
}

// async global->LDS, 16B per lane. LDS dest = base + lane*16 (wave-uniform base).
__device__ __forceinline__ void gload_lds16(const u16* g, u16* l) {
  __builtin_amdgcn_global_load_lds((const __attribute__((address_space(1))) unsigned int*)g,
                                   (__attribute__((address_space(3))) unsigned int*)l, 16, 0, 0);
}

// ---------------------------------------------------------------- fused prologue
__global__ __launch_bounds__(256) void prep_kernel(const float* __restrict__ x,
                                                   u16* __restrict__ xb,
                                                   u16* __restrict__ xlo,
                                                   const float* __restrict__ W1,
                                                   u16* __restrict__ W1Th,
                                                   u16* __restrict__ W1Tl,
                                                   const float* __restrict__ Wq,
                                                   u16* __restrict__ WqT,
                                                   const float* __restrict__ Wkv,
                                                   u16* __restrict__ WkvT,
                                                   const float* __restrict__ Wo,
                                                   u16* __restrict__ WoT,
                                                   float* __restrict__ cosT,
                                                   float* __restrict__ sinT) {
  __shared__ u16 tH[64][72];
  __shared__ u16 tL[64][72];
  int bid = blockIdx.x;
  const int t = threadIdx.x;

  if (bid < 8192) {  // cvt_x
    size_t base = ((size_t)bid * 256 + t) * 8;
    short8 hi, lo;
    #pragma unroll
    for (int i = 0; i < 8; ++i) {
      float v = x[base + i];
      u16 h = f2bf(v);
      hi[i] = (short)h;
      lo[i] = (short)f2bf(v - bf2f(h));
    }
    *(short8*)&xb[base] = hi;
    *(short8*)&xlo[base] = lo;
    return;
  }
  bid -= 8192;

  if (bid >= 2816) {  // rope tables
    int gid = (bid - 2816) * 256 + t;
    int pos = gid >> 6, i = gid & 63;
    float e = (float)(2 * i) * (1.0f / 128.0f);
    float inv = powf(10000.0f, -e);
    float ang = (float)pos * inv;
    cosT[pos * 64 + i] = cosf(ang);
    sinT[pos * 64 + i] = sinf(ang);
    return;
  }

  const float* in;
  u16* oH;
  u16* oL = nullptr;
  int R, C, bx, by;
  if (bid < 256) {
    in = W1; oH = W1Th; oL = W1Tl; R = 2048; C = 512; bx = bid & 7; by = bid >> 3;
  } else if (bid < 1280) {
    bid -= 256;
    in = Wq; oH = WqT; R = 2048; C = 2048; bx = bid & 31; by = bid >> 5;
  } else if (bid < 1792) {
    bid -= 1280;
    in = Wkv; oH = WkvT; R = 2048; C = 1024; bx = bid & 15; by = bid >> 4;
  } else {
    bid -= 1792;
    in = Wo; oH = WoT; R = 2048; C = 2048; bx = bid & 31; by = bid >> 5;
  }
  int rb = by * 64, cb = bx * 64;
  #pragma unroll
  for (int i = 0; i < 16; ++i) {
    int r = i * 4 + (t >> 6), c = t & 63;
    float v = in[(size_t)(rb + r) * C + cb + c];
    u16 h = f2bf(v);
    tH[r][c] = h;
    if (oL) tL[r][c] = f2bf(v - bf2f(h));
  }
  __syncthreads();
  #pragma unroll
  for (int i = 0; i < 16; ++i) {
    int r = i * 4 + (t >> 6), c = t & 63;
    oH[(size_t)(cb + r) * R + rb + c] = tH[c][r];
    if (oL) oL[(size_t)(cb + r) * R + rb + c] = tL[c][r];
  }
}

// ---------------------------------------------------------------- 256x256 pipelined GEMM  C = A @ B^T
template <bool BF16OUT>
__global__ __launch_bounds__(512, 2) void gemm256(const u16* __restrict__ A,
                                                  const u16* __restrict__ BT,
                                                  float* __restrict__ Cf,
                                                  u16* __restrict__ Cb,
                                                  int M, int N, int K) {
  __shared__ __align__(1024) u16 smem[65536];
  const int bm = blockIdx.x * 256, bn = blockIdx.y * 256;
  const int t = threadIdx.x, lane = t & 63, w = t >> 6;
  const int ll = lane & 15, lh = lane >> 4;
  const int wr = w >> 2, wc = w & 3;
  const int NT = K >> 6;

  const int tt0 = t, tt1 = t + 512;
  const int r0 = tt0 >> 2, r1 = tt1 >> 2;
  const int c0 = (((tt0 & 3) ^ ((tt0 >> 3) & 3)) << 3);
  const int c1 = (((tt1 & 3) ^ ((tt1 >> 3) & 3)) << 3);
  const size_t aoff0 = (size_t)(bm + r0) * K + c0;
  const size_t aoff1 = (size_t)(bm + r1) * K + c1;
  const size_t boff0 = (size_t)(bn + r0) * K + c0;
  const size_t boff1 = (size_t)(bn + r1) * K + c1;

  const int swz = ((lh ^ ((ll >> 1) & 3)) << 3);
  const int arow = (wr * 128 + ll) * 32 + swz;
  const int brow = (wc * 64 + ll) * 32 + swz;

  f32x4 acc[8][4];
  #pragma unroll
  for (int mi = 0; mi < 8; ++mi)
    #pragma unroll
    for (int ni = 0; ni < 4; ++ni) acc[mi][ni] = f32x4{0.f, 0.f, 0.f, 0.f};

  short8 aq[8], bq[2];

#define G_STAGE(base, o0, o1, lds) \
  gload_lds16((base) + (o0), (lds) + w * 512); \
  gload_lds16((base) + (o1), (lds) + 4096 + w * 512)
#define RD_A(Sa, ks) \
  _Pragma("unroll") for (int mi = 0; mi < 8; ++mi) aq[mi] = *(const short8*)&(Sa)[(ks)*8192 + arow + mi * 512]
#define RD_B(Sb, ks, nh) \
  _Pragma("unroll") for (int n2 = 0; n2 < 2; ++n2) bq[n2] = *(const short8*)&(Sb)[(ks)*8192 + brow + ((nh)*2 + n2) * 512]
#define DO_MFMA(nh) \
  __builtin_amdgcn_s_setprio(1); \
  _Pragma("unroll") for (int mi = 0; mi < 8; ++mi) \
    _Pragma("unroll") for (int n2 = 0; n2 < 2; ++n2) \
      acc[mi][(nh)*2 + n2] = __builtin_amdgcn_mfma_f32_16x16x32_bf16(aq[mi], bq[n2], acc[mi][(nh)*2 + n2], 0, 0, 0); \
  __builtin_amdgcn_s_setprio(0)
#define VMW(n) asm volatile("s_waitcnt vmcnt(" #n ")" ::: "memory")

  G_STAGE(A, aoff0, aoff1, smem);
  G_STAGE(BT, boff0, boff1, smem + 16384);
  G_STAGE(A, aoff0 + 32, aoff1 + 32, smem + 8192);
  G_STAGE(BT, boff0 + 32, boff1 + 32, smem + 16384 + 8192);

  for (int kt = 0; kt < NT - 1; ++kt) {
    const int cur = kt & 1;
    u16* Sa = smem + cur * 32768;
    u16* Sb = Sa + 16384;
    u16* Pa = smem + (cur ^ 1) * 32768;
    u16* Pb = Pa + 16384;
    const size_t kg = (size_t)(kt + 1) * 64;
    VMW(4);
    __builtin_amdgcn_s_barrier();
    G_STAGE(A, aoff0 + kg, aoff1 + kg, Pa);
    RD_A(Sa, 0);
    RD_B(Sb, 0, 0);
    DO_MFMA(0);
    __builtin_amdgcn_s_barrier();
    G_STAGE(BT, boff0 + kg, boff1 + kg, Pb);
    RD_B(Sb, 0, 1);
    DO_MFMA(1);
    VMW(4);
    __builtin_amdgcn_s_barrier();
    G_STAGE(A, aoff0 + kg + 32, aoff1 + kg + 32, Pa + 8192);
    RD_A(Sa, 1);
    RD_B(Sb, 1, 0);
    DO_MFMA(0);
    __builtin_amdgcn_s_barrier();
    G_STAGE(BT, boff0 + kg + 32, boff1 + kg + 32, Pb + 8192);
    RD_B(Sb, 1, 1);
    DO_MFMA(1);
  }
  {
    const int cur = (NT - 1) & 1;
    u16* Sa = smem + cur * 32768;
    u16* Sb = Sa + 16384;
    VMW(4);
    __builtin_amdgcn_s_barrier();
    RD_A(Sa, 0); RD_B(Sb, 0, 0); DO_MFMA(0);
    __builtin_amdgcn_s_barrier();
    RD_B(Sb, 0, 1); DO_MFMA(1);
    VMW(0);
    __builtin_amdgcn_s_barrier();
    RD_A(Sa, 1); RD_B(Sb, 1, 0); DO_MFMA(0);
    __builtin_amdgcn_s_barrier();
    RD_B(Sb, 1, 1); DO_MFMA(1);
  }

  #pragma unroll
  for (int mi = 0; mi < 8; ++mi)
    #pragma unroll
    for (int ni = 0; ni < 4; ++ni)
      #pragma unroll
      for (int r = 0; r < 4; ++r) {
        int row = bm + wr * 128 + mi * 16 + lh * 4 + r;
        int col = bn + wc * 64 + ni * 16 + ll;
        float v = acc[mi][ni][r];
        if (BF16OUT) Cb[(size_t)row * N + col] = f2bf(v);
        else Cf[(size_t)row * N + col] = v;
      }
#undef G_STAGE
#undef RD_A
#undef RD_B
#undef DO_MFMA
#undef VMW
}

// ---------------------------------------------------------------- gathered-A GEMM (split-K, pipelined async)
__global__ __launch_bounds__(256) void gemm_bt_gather(const u16* __restrict__ A,
                                                      const u16* __restrict__ BT,
                                                      const int* __restrict__ rowidx,
                                                      float* __restrict__ Cpart,
                                                      int M, int N, int K) {
  __shared__ __align__(1024) u16 smem[32768];  // 2 bufs x (A 8192 + B 8192)
  const int bm = blockIdx.x * 128, bn = blockIdx.y * 128;
  const int kz = blockIdx.z;
  const int t = threadIdx.x, lane = t & 63, w = t >> 6;
  const int lh = lane >> 4, ll = lane & 15;
  const int wm = (w >> 1) * 64, wn = (w & 1) * 64;

  size_t aoff[4], boff[4];
  #pragma unroll
  for (int i = 0; i < 4; ++i) {
    int c = i * 256 + t;
    int row = c >> 3;
    int gslot = (c & 7) ^ (row & 7);
    aoff[i] = (size_t)rowidx[bm + row] * K + gslot * 8;
    boff[i] = (size_t)(bn + row) * K + gslot * 8;
  }

  f32x4 acc[4][4];
  #pragma unroll
  for (int mt = 0; mt < 4; ++mt)
    #pragma unroll
    for (int nt = 0; nt < 4; ++nt) acc[mt][nt] = f32x4{0.f, 0.f, 0.f, 0.f};

#define GA_STAGE(buf, kb) \
  _Pragma("unroll") for (int i = 0; i < 4; ++i) { \
    int c = i * 256 + t; \
    gload_lds16(A + aoff[i] + (kb), (buf) + c * 8); \
    gload_lds16(BT + boff[i] + (kb), (buf) + 8192 + c * 8); \
  }
#define GVMW(n) asm volatile("s_waitcnt vmcnt(" #n ")" ::: "memory")

  const int k0 = kz * (K / 2);
  const int NT = (K / 2) / 64;  // 16

  GA_STAGE(smem, k0);

  for (int kt = 0; kt < NT; ++kt) {
    const int cur = kt & 1;
    u16* S = smem + cur * 16384;
    if (kt + 1 < NT) {
      GA_STAGE(smem + (cur ^ 1) * 16384, k0 + (kt + 1) * 64);
      GVMW(8);
    } else {
      GVMW(0);
    }
    __builtin_amdgcn_s_barrier();
    #pragma unroll
    for (int ks = 0; ks < 2; ++ks) {
      short8 a[4], b[4];
      #pragma unroll
      for (int mt = 0; mt < 4; ++mt) {
        int row = wm + mt * 16 + ll;
        int p = (ks * 4 + lh) ^ (row & 7);
        a[mt] = *(const short8*)&S[row * 64 + p * 8];
      }
      #pragma unroll
      for (int nt = 0; nt < 4; ++nt) {
        int row = wn + nt * 16 + ll;
        int p = (ks * 4 + lh) ^ (row & 7);
        b[nt] = *(const short8*)&S[8192 + row * 64 + p * 8];
      }
      __builtin_amdgcn_s_setprio(1);
      #pragma unroll
      for (int mt = 0; mt < 4; ++mt)
        #pragma unroll
        for (int nt = 0; nt < 4; ++nt)
          acc[mt][nt] = __builtin_amdgcn_mfma_f32_16x16x32_bf16(a[mt], b[nt], acc[mt][nt], 0, 0, 0);
      __builtin_amdgcn_s_setprio(0);
    }
    __builtin_amdgcn_s_barrier();
  }

  float* C = Cpart + (size_t)kz * M * N;
  #pragma unroll
  for (int mt = 0; mt < 4; ++mt)
    #pragma unroll
    for (int nt = 0; nt < 4; ++nt)
      #pragma unroll
      for (int r = 0; r < 4; ++r) {
        int row = bm + wm + mt * 16 + lh * 4 + r;
        int col = bn + wn + nt * 16 + ll;
        C[(size_t)row * N + col] = acc[mt][nt][r];
      }
#undef GA_STAGE
#undef GVMW
}

// ---------------------------------------------------------------- scorer GEMM (3-term hi/lo, depth-2 pipeline)
__global__ __launch_bounds__(512) void gemm_scorer(const u16* __restrict__ Ahi,
                                                   const u16* __restrict__ Alo,
                                                   const u16* __restrict__ Bhi,
                                                   const u16* __restrict__ Blo,
                                                   float* __restrict__ Cpart,
                                                   int M, int N, int K) {
  __shared__ __align__(1024) u16 smem[73728];  // 3 bufs x 24576 elems
  const int bm = blockIdx.x * 256, bn = blockIdx.y * 128;
  const int kz = blockIdx.z;
  const int t = threadIdx.x, lane = t & 63, w = t >> 6;
  const int ll = lane & 15, lh = lane >> 4;
  const int wr = w >> 2, wc = w & 3;

  const int cA0 = (w * 2) * 64 + lane;
  const int cA1 = (w * 2 + 1) * 64 + lane;
  const int cB = w * 64 + lane;
  const size_t offA0 = (size_t)(bm + (cA0 >> 2)) * K + (((cA0 & 3) ^ ((cA0 >> 3) & 3)) << 3);
  const size_t offA1 = (size_t)(bm + (cA1 >> 2)) * K + (((cA1 & 3) ^ ((cA1 >> 3) & 3)) << 3);
  const size_t offB = (size_t)(bn + (cB >> 2)) * K + (((cB & 3) ^ ((cB >> 3) & 3)) << 3);

  const int arow = wr * 128 + ll;
  const int brow = wc * 32 + ll;

  f32x4 acc[8][2];
  #pragma unroll
  for (int mi = 0; mi < 8; ++mi)
    #pragma unroll
    for (int ni = 0; ni < 2; ++ni) acc[mi][ni] = f32x4{0.f, 0.f, 0.f, 0.f};

#define S_STAGE(buf, kb) \
  gload_lds16(Ahi + offA0 + (kb), (buf) + cA0 * 8); \
  gload_lds16(Ahi + offA1 + (kb), (buf) + cA1 * 8); \
  gload_lds16(Alo + offA0 + (kb), (buf) + 8192 + cA0 * 8); \
  gload_lds16(Alo + offA1 + (kb), (buf) + 8192 + cA1 * 8); \
  gload_lds16(Bhi + offB + (kb), (buf) + 16384 + cB * 8); \
  gload_lds16(Blo + offB + (kb), (buf) + 20480 + cB * 8)
#define SVMW(n) asm volatile("s_waitcnt vmcnt(" #n ")" ::: "memory")

  const int k0 = kz * (K / 2);
  const int NT = (K / 2) / 32;  // 32

  S_STAGE(smem, k0);
  S_STAGE(smem + 24576, k0 + 32);

  for (int kt = 0; kt < NT; ++kt) {
    u16* S = smem + (kt % 3) * 24576;
    if (kt + 1 < NT) { SVMW(6); } else { SVMW(0); }
    __builtin_amdgcn_s_barrier();
    if (kt + 2 < NT) { S_STAGE(smem + ((kt + 2) % 3) * 24576, k0 + (kt + 2) * 32); }

    short8 aH[8], aL[8], bH[2], bL[2];
    #pragma unroll
    for (int mi = 0; mi < 8; ++mi) {
      int r = arow + mi * 16;
      int o = r * 32 + ((lh ^ ((r >> 1) & 3)) << 3);
      aH[mi] = *(const short8*)&S[o];
      aL[mi] = *(const short8*)&S[8192 + o];
    }
    #pragma unroll
    for (int ni = 0; ni < 2; ++ni) {
      int r = brow + ni * 16;
      int o = r * 32 + ((lh ^ ((r >> 1) & 3)) << 3);
      bH[ni] = *(const short8*)&S[16384 + o];
      bL[ni] = *(const short8*)&S[20480 + o];
    }
    __builtin_amdgcn_s_setprio(1);
    #pragma unroll
    for (int mi = 0; mi < 8; ++mi)
      #pragma unroll
      for (int ni = 0; ni < 2; ++ni)
        acc[mi][ni] = __builtin_amdgcn_mfma_f32_16x16x32_bf16(aH[mi], bH[ni], acc[mi][ni], 0, 0, 0);
    __builtin_amdgcn_s_setprio(0);
    __builtin_amdgcn_s_setprio(1);
    #pragma unroll
    for (int mi = 0; mi < 8; ++mi)
      #pragma unroll
      for (int ni = 0; ni < 2; ++ni)
        acc[mi][ni] = __builtin_amdgcn_mfma_f32_16x16x32_bf16(aH[mi], bL[ni], acc[mi][ni], 0, 0, 0);
    __builtin_amdgcn_s_setprio(0);
    __builtin_amdgcn_s_setprio(1);
    #pragma unroll
    for (int mi = 0; mi < 8; ++mi)
      #pragma unroll
      for (int ni = 0; ni < 2; ++ni)
        acc[mi][ni] = __builtin_amdgcn_mfma_f32_16x16x32_bf16(aL[mi], bH[ni], acc[mi][ni], 0, 0, 0);
    __builtin_amdgcn_s_setprio(0);
    __builtin_amdgcn_s_barrier();
  }

  float* C = Cpart + (size_t)kz * M * N;
  #pragma unroll
  for (int mi = 0; mi < 8; ++mi)
    #pragma unroll
    for (int ni = 0; ni < 2; ++ni)
      #pragma unroll
      for (int r = 0; r < 4; ++r) {
        int row = bm + wr * 128 + mi * 16 + lh * 4 + r;
        int col = bn + wc * 32 + ni * 16 + ll;
        C[(size_t)row * N + col] = acc[mi][ni][r];
      }
#undef S_STAGE
#undef SVMW
}

// ---------------------------------------------------------------- scorer finish
__global__ __launch_bounds__(256) void scorer_finish(const float* __restrict__ hg,
                                                     const float* __restrict__ b1,
                                                     const float* __restrict__ W2,
                                                     const float* __restrict__ b2,
                                                     float* __restrict__ imp) {
  int tok = blockIdx.x * 4 + (threadIdx.x >> 6);
  int lane = threadIdx.x & 63;
  const float* h0 = hg + (size_t)tok * 512;
  const float* h1 = hg + (size_t)8192 * 512 + (size_t)tok * 512;
  float s = 0.f;
  #pragma unroll
  for (int i = 0; i < 8; ++i) {
    int c = lane + i * 64;
    float v = h0[c] + h1[c] + b1[c];
    v = 0.5f * v * (1.0f + erff(v * 0.70710678118654752f));
    s += v * W2[c];
  }
  #pragma unroll
  for (int off = 32; off; off >>= 1) s += __shfl_xor(s, off, 64);
  if (lane == 0) imp[tok] = s + b2[0];
}

// ---------------------------------------------------------------- top-k via exact radix-select
// Keys: order-transformed fp32 bits (monotonic unsigned). 4 MSB-first 8-bit passes
// find the 512th-largest key K* and residual 'need' among ties (tie-break = index
// ascending, matching lax.top_k). One packed pair-scan then emits the selected set
// in ascending-index order: pos = (#gt before) + min(#eq before, need).
__global__ __launch_bounds__(1024) void topk_kernel(const float* __restrict__ imp,
                                                    int* __restrict__ idx_sel,
                                                    int* __restrict__ sel_rows,
                                                    float* __restrict__ gatev) {
  __shared__ unsigned key[2048];
  __shared__ unsigned suff[256];
  __shared__ unsigned ps[1024];
  __shared__ unsigned sh_known, sh_need;
  const int b = blockIdx.x, t = threadIdx.x;
  const int lane = t & 63;

  for (int i = t; i < 2048; i += 1024) {
    unsigned u = __float_as_uint(imp[b * 2048 + i]);
    key[i] = u ^ ((u & 0x80000000u) ? 0xFFFFFFFFu : 0x80000000u);
  }
  if (t == 0) { sh_known = 0u; sh_need = 512u; }
  __syncthreads();

  unsigned kmask = 0u;
  #pragma unroll
  for (int shift = 24; shift >= 0; shift -= 8) {
    unsigned known = sh_known;
    if (t < 256) suff[t] = 0u;
    __syncthreads();
    for (int i = t; i < 2048; i += 1024)
      if ((key[i] & kmask) == known) atomicAdd(&suff[(key[i] >> shift) & 255], 1u);
    __syncthreads();
    // wave 0: in-place suffix sums over 256 bins (lane covers bins 4l..4l+3)
    if (t < 64) {
      unsigned cbin0 = suff[4 * lane], cbin1 = suff[4 * lane + 1];
      unsigned cbin2 = suff[4 * lane + 2], cbin3 = suff[4 * lane + 3];
      unsigned s = cbin0 + cbin1 + cbin2 + cbin3;
      unsigned acc = s;
      #pragma unroll
      for (int off = 1; off < 64; off <<= 1) {
        unsigned tmp = __shfl_down(acc, off, 64);
        if (lane + off < 64) acc += tmp;
      }
      unsigned sfx = acc - s;  // strict suffix of lane sums
      suff[4 * lane + 3] = sfx + cbin3;
      suff[4 * lane + 2] = sfx + cbin3 + cbin2;
      suff[4 * lane + 1] = sfx + cbin3 + cbin2 + cbin1;
      suff[4 * lane]     = sfx + cbin3 + cbin2 + cbin1 + cbin0;
    }
    __syncthreads();
    // exactly one bin satisfies: suff[beta] >= need > suff[beta+1]
    unsigned need = sh_need;
    if (t < 256) {
      unsigned above = (t == 255) ? 0u : suff[t + 1];
      if (suff[t] >= need && above < need) {
        sh_known = known | ((unsigned)t << shift);
        sh_need = need - above;
      }
    }
    __syncthreads();
    kmask |= (255u << shift);
  }

  const unsigned Kstar = sh_known;
  const unsigned need = sh_need;  // take this many of the == Kstar keys, by index asc

  // packed indicators: high half = (key == Kstar), low half = (key > Kstar)
  unsigned k0 = key[2 * t], k1 = key[2 * t + 1];
  unsigned a0 = ((k0 == Kstar) ? 0x10000u : 0u) | ((k0 > Kstar) ? 1u : 0u);
  unsigned a1 = ((k1 == Kstar) ? 0x10000u : 0u) | ((k1 > Kstar) ? 1u : 0u);
  ps[t] = a0 + a1;
  __syncthreads();
  for (int off = 1; off < 1024; off <<= 1) {
    unsigned add = (t >= off) ? ps[t - off] : 0u;
    __syncthreads();
    ps[t] += add;
    __syncthreads();
  }
  unsigned ex0 = (t == 0) ? 0u : ps[t - 1];  // exclusive prefix for element 2t
  unsigned ex1 = ex0 + a0;                   // for element 2t+1

  #pragma unroll
  for (int e = 0; e < 2; ++e) {
    int i = 2 * t + e;
    unsigned k = e ? k1 : k0;
    unsigned ex = e ? ex1 : ex0;
    unsigned eqr = ex >> 16, gtc = ex & 0xFFFFu;
    bool sel = (k > Kstar) || ((k == Kstar) && eqr < need);
    if (sel) {
      unsigned pos = gtc + ((eqr < need) ? eqr : need);
      idx_sel[b * 512 + pos] = i;
      sel_rows[b * 512 + pos] = b * 2048 + i;
      float g = imp[b * 2048 + i];
      gatev[b * 512 + pos] = 1.0f / (1.0f + __expf(-g));
    }
  }
}

// ---------------------------------------------------------------- fused K-rope + gated V^T from fp32 partials
__global__ __launch_bounds__(256) void kv_finish(const float* __restrict__ part,
                                                 const int* __restrict__ idx_sel,
                                                 const float* __restrict__ cosT,
                                                 const float* __restrict__ sinT,
                                                 const float* __restrict__ gatev,
                                                 u16* __restrict__ Kb,
                                                 u16* __restrict__ VT) {
  int gid = blockIdx.x * 256 + threadIdx.x;
  if (gid < (1 << 19)) {
    int i = gid & 63;
    int s = (gid >> 6) & 511;
    int kvh = (gid >> 15) & 3;
    int b = gid >> 17;
    size_t src = (size_t)(b * 512 + s) * 1024 + kvh * 128 + i;
    float k1 = part[src] + part[src + 2097152];
    float k2 = part[src + 64] + part[src + 64 + 2097152];
    int pos = idx_sel[b * 512 + s];
    float c = cosT[pos * 64 + i], sn = sinT[pos * 64 + i];
    size_t dst = (size_t)((b * 4 + kvh) * 512 + s) * 128 + i;
    Kb[dst] = f2bf(k1 * c - k2 * sn);
    Kb[dst + 64] = f2bf(k1 * sn + k2 * c);
  } else {
    int g2 = gid - (1 << 19);
    int s = g2 & 511;
    int d = (g2 >> 9) & 127;
    int kvh = (g2 >> 16) & 3;
    int b = g2 >> 18;
    size_t src = (size_t)(b * 512 + s) * 1024 + 512 + kvh * 128 + d;
    float v = part[src] + part[src + 2097152];
    VT[(size_t)((b * 4 + kvh) * 128 + d) * 512 + s] = f2bf(v * gatev[b * 512 + s]);
  }
}

// ---------------------------------------------------------------- flash attention
__global__ __launch_bounds__(512) void attn_kernel(const u16* __restrict__ Qb,
                                                   const u16* __restrict__ Kb,
                                                   const u16* __restrict__ VTb,
                                                   const int* __restrict__ idxp,
                                                   const float* __restrict__ cosT,
                                                   const float* __restrict__ sinT,
                                                   u16* __restrict__ Ob) {
  __shared__ u16 Ks[64][132];   // 16896B
  __shared__ u16 Vs[128][76];   // 19456B
  __shared__ u16 Ps[8][16][68]; // 17408B
  __shared__ int idx_s[64];     // 256B   -> total 54016B, 3 blocks/CU

  const int qt = (blockIdx.x + 4 * blockIdx.z) & 15;  // de-alias qt from CU id
  const int h = blockIdx.y, b = blockIdx.z;
  const int kvh = h >> 2;
  const int t = threadIdx.x, lane = t & 63, w = t >> 6;
  const int lh = lane >> 4, ll = lane & 15;
  const int q0 = qt * 128;
  const float SCALE_LOG2E = 0.12753102331f;  // HD^-0.5 * log2(e)

  int NT = 8;
  if (idxp[b * 512] <= q0) {
    NT = 1;
    while (NT < 8 && idxp[b * 512 + NT * 64] <= q0 + 127) ++NT;
  }

  const int lrow = q0 + w * 16 + ll;
  short8 aq[4];
  #pragma unroll
  for (int ks = 0; ks < 4; ++ks)
    aq[ks] = *(const short8*)&Qb[(size_t)(b * 2048 + lrow) * 2048 + h * 128 + ks * 32 + lh * 8];
  {
    const float* cp = cosT + (size_t)lrow * 64 + lh * 8;
    const float* sp = sinT + (size_t)lrow * 64 + lh * 8;
    short8 n0, n1, n2, n3;
    #pragma unroll
    for (int j = 0; j < 8; ++j) {
      float cA = cp[j], sA = sp[j], cB = cp[32 + j], sB = sp[32 + j];
      float x0 = bf2f((u16)aq[0][j]), x2 = bf2f((u16)aq[2][j]);
      float x1 = bf2f((u16)aq[1][j]), x3 = bf2f((u16)aq[3][j]);
      n0[j] = (short)f2bf(x0 * cA - x2 * sA);
      n2[j] = (short)f2bf(x0 * sA + x2 * cA);
      n1[j] = (short)f2bf(x1 * cB - x3 * sB);
      n3[j] = (short)f2bf(x1 * sB + x3 * cB);
    }
    aq[0] = n0; aq[1] = n1; aq[2] = n2; aq[3] = n3;
  }

  float m[4], lden[4];
  f32x4 O[8];
  #pragma unroll
  for (int r = 0; r < 4; ++r) { m[r] = -INFINITY; lden[r] = 0.f; }
  #pragma unroll
  for (int dt = 0; dt < 8; ++dt) O[dt] = f32x4{0.f, 0.f, 0.f, 0.f};

  for (int kt = 0; kt < NT; ++kt) {
    const int tmax = idxp[b * 512 + kt * 64 + 63];
    const bool nomask = (tmax <= q0 + w * 16);  // wave-uniform

    __syncthreads();
    #pragma unroll
    for (int i = 0; i < 2; ++i) {
      int e = t + i * 512;
      int krow = e >> 4, kc8 = e & 15;
      *(short8*)&Ks[krow][kc8 * 8] =
          *(const short8*)&Kb[(size_t)((b * 4 + kvh) * 512 + kt * 64 + krow) * 128 + kc8 * 8];
      int vrow = e >> 3, vc8 = e & 7;
      *(short8*)&Vs[vrow][vc8 * 8] =
          *(const short8*)&VTb[(size_t)((b * 4 + kvh) * 128 + vrow) * 512 + kt * 64 + vc8 * 8];
    }
    if (t < 64) idx_s[t] = idxp[b * 512 + kt * 64 + t];
    __syncthreads();

    f32x4 S[4];
    #pragma unroll
    for (int nt = 0; nt < 4; ++nt) S[nt] = f32x4{0.f, 0.f, 0.f, 0.f};
    __builtin_amdgcn_s_setprio(1);
    #pragma unroll
    for (int nt = 0; nt < 4; ++nt)
      #pragma unroll
      for (int ks = 0; ks < 4; ++ks) {
        short8 bk = *(const short8*)&Ks[nt * 16 + ll][ks * 32 + lh * 8];
        S[nt] = __builtin_amdgcn_mfma_f32_16x16x32_bf16(aq[ks], bk, S[nt], 0, 0, 0);
      }
    __builtin_amdgcn_s_setprio(0);

    float p[4][4], lmax[4];
    #pragma unroll
    for (int r = 0; r < 4; ++r) lmax[r] = -INFINITY;
    if (nomask) {
      #pragma unroll
      for (int nt = 0; nt < 4; ++nt)
        #pragma unroll
        for (int r = 0; r < 4; ++r) {
          float s = S[nt][r] * SCALE_LOG2E;
          p[nt][r] = s;
          lmax[r] = fmaxf(lmax[r], s);
        }
    } else {
      #pragma unroll
      for (int nt = 0; nt < 4; ++nt) {
        int kpos = idx_s[nt * 16 + ll];
        #pragma unroll
        for (int r = 0; r < 4; ++r) {
          int row = q0 + w * 16 + lh * 4 + r;
          float s = S[nt][r] * SCALE_LOG2E;
          if (kpos > row) s = -1e9f;
          p[nt][r] = s;
          lmax[r] = fmaxf(lmax[r], s);
        }
      }
    }
    #pragma unroll
    for (int off = 8; off; off >>= 1)
      #pragma unroll
      for (int r = 0; r < 4; ++r) lmax[r] = fmaxf(lmax[r], __shfl_xor(lmax[r], off, 64));

    bool need = false;
    #pragma unroll
    for (int r = 0; r < 4; ++r) need = need || (lmax[r] > m[r] + 8.0f);
    if (__any(need)) {
      #pragma unroll
      for (int r = 0; r < 4; ++r) {
        float mnew = fmaxf(m[r], lmax[r]);
        float alpha = exp2f(m[r] - mnew);
        m[r] = mnew;
        lden[r] *= alpha;
        #pragma unroll
        for (int dt = 0; dt < 8; ++dt) O[dt][r] *= alpha;
      }
    }

    float rs[4] = {0.f, 0.f, 0.f, 0.f};
    #pragma unroll
    for (int nt = 0; nt < 4; ++nt)
      #pragma unroll
      for (int r = 0; r < 4; ++r) {
        float e = exp2f(p[nt][r] - m[r]);
        p[nt][r] = e;
        rs[r] += e;
      }
    #pragma unroll
    for (int off = 8; off; off >>= 1)
      #pragma unroll
      for (int r = 0; r < 4; ++r) rs[r] += __shfl_xor(rs[r], off, 64);
    #pragma unroll
    for (int r = 0; r < 4; ++r) lden[r] += rs[r];

    #pragma unroll
    for (int nt = 0; nt < 4; ++nt)
      #pragma unroll
      for (int r = 0; r < 4; r += 2) {
        unsigned pk;
        asm("v_cvt_pk_bf16_f32 %0, %1, %2" : "=v"(pk) : "v"(p[nt][r]), "v"(p[nt][r + 1]));
        Ps[w][lh * 4 + r][nt * 16 + ll] = (u16)pk;
        Ps[w][lh * 4 + r + 1][nt * 16 + ll] = (u16)(pk >> 16);
      }
    __builtin_amdgcn_s_setprio(1);
    #pragma unroll
    for (int ks = 0; ks < 2; ++ks) {
      short8 pa = *(const short8*)&Ps[w][ll][ks * 32 + lh * 8];
      #pragma unroll
      for (int dt = 0; dt < 8; ++dt) {
        short8 vb = *(const short8*)&Vs[dt * 16 + ll][ks * 32 + lh * 8];
        O[dt] = __builtin_amdgcn_mfma_f32_16x16x32_bf16(pa, vb, O[dt], 0, 0, 0);
      }
    }
    __builtin_amdgcn_s_setprio(0);
  }

  #pragma unroll
  for (int dt = 0; dt < 8; ++dt)
    #pragma unroll
    for (int r = 0; r < 4; ++r) {
      int row = q0 + w * 16 + lh * 4 + r;
      int col = h * 128 + dt * 16 + ll;
      Ob[(size_t)(b * 2048 + row) * 2048 + col] = f2bf(O[dt][r] / lden[r]);
    }
}

// ================================================================ launch
extern "C" void kernel_launch(void* const* d_in, const int* in_sizes, int n_in,
                              void* d_out, int out_size, void* d_ws, size_t ws_size,
                              hipStream_t stream) {
  const float* x = (const float*)d_in[0];
  const float* Wq = (const float*)d_in[1];
  const float* Wkv = (const float*)d_in[2];
  const float* Wo = (const float*)d_in[3];
  const float* W1 = (const float*)d_in[4];
  const float* b1 = (const float*)d_in[5];
  const float* W2 = (const float*)d_in[6];
  const float* b2 = (const float*)d_in[7];
  float* out = (float*)d_out;

  char* ws = (char*)d_ws;
  size_t off = 0;
  auto alloc = [&](size_t bytes) {
    char* p = ws + off;
    off = (off + bytes + 255) & ~(size_t)255;
    return p;
  };
  u16* xb = (u16*)alloc((size_t)8192 * 2048 * 2);
  u16* xlo = (u16*)alloc((size_t)8192 * 2048 * 2);   // dead after scorer GEMM
  u16* W1Th = (u16*)alloc((size_t)512 * 2048 * 2);
  u16* W1Tl = (u16*)alloc((size_t)512 * 2048 * 2);
  u16* WqT = (u16*)alloc((size_t)2048 * 2048 * 2);
  u16* WkvT = (u16*)alloc((size_t)1024 * 2048 * 2);
  u16* WoT = (u16*)alloc((size_t)2048 * 2048 * 2);
  float* cosT = (float*)alloc((size_t)2048 * 64 * 4);
  float* sinT = (float*)alloc((size_t)2048 * 64 * 4);
  float* hg = (float*)alloc((size_t)2 * 8192 * 512 * 4);  // scorer partials; later reused for kv partials
  float* impv = (float*)alloc((size_t)8192 * 4);
  int* idx_sel = (int*)alloc((size_t)2048 * 4);
  int* sel_rows = (int*)alloc((size_t)2048 * 4);
  float* gatev = (float*)alloc((size_t)2048 * 4);
  u16* qbuf = (u16*)alloc((size_t)8192 * 2048 * 2);
  u16* Kbuf = (u16*)alloc((size_t)4 * 4 * 512 * 128 * 2);
  u16* VTbuf = (u16*)alloc((size_t)4 * 4 * 128 * 512 * 2);
  u16* attn_out = xlo;          // alias: xlo dead before attention writes
  float* kvpart = hg;           // alias: hg dead after topk (needs 16MB of hg's 32MB)

  // fused prologue: cvt_x + 4 weight transposes + rope tables in ONE launch
  prep_kernel<<<11520, 256, 0, stream>>>(x, xb, xlo, W1, W1Th, W1Tl, Wq, WqT,
                                         Wkv, WkvT, Wo, WoT, cosT, sinT);

  // scorer: depth-2 pipelined split-K partials, then fused finish (bias+gelu+W2+b2)
  gemm_scorer<<<dim3(32, 4, 2), 512, 0, stream>>>(xb, xlo, W1Th, W1Tl, hg, 8192, 512, 2048);
  scorer_finish<<<2048, 256, 0, stream>>>(hg, b1, W2, b2, impv);
  topk_kernel<<<4, 1024, 0, stream>>>(impv, idx_sel, sel_rows, gatev);

  // q = x@Wq (bf16, 256x256 pipelined); RoPE applied inside attention
  gemm256<true><<<dim3(32, 8), 512, 0, stream>>>(xb, WqT, nullptr, qbuf, 8192, 2048, 2048);

  // kv on gathered rows (pipelined split-K fp32 partials), then fused K-rope + gated V^T
  gemm_bt_gather<<<dim3(16, 8, 2), 256, 0, stream>>>(xb, WkvT, sel_rows, kvpart, 2048, 1024, 2048);
  kv_finish<<<6144, 256, 0, stream>>>(kvpart, idx_sel, cosT, sinT, gatev, Kbuf, VTbuf);

  // attention (LDS-staged, 3 blocks/CU, qt de-aliased, fused RoPE-Q, T5 setprio)
  attn_kernel<<<dim3(16, 16, 4), 512, 0, stream>>>(qbuf, Kbuf, VTbuf, idx_sel, cosT, sinT, attn_out);

  // output projection -> fp32 d_out (256x256 pipelined, phase-split)
  gemm256<false><<<dim3(32, 8), 512, 0, stream>>>(attn_out, WoT, out, nullptr, 8192, 2048, 2048);
}